// Round 1
// baseline (124.943 us; speedup 1.0000x reference)
//
#include <hip/hip_runtime.h>
#include <math.h>

#define NPTS 1024
#define THREADS 256

__device__ __forceinline__ float wave_red_f(float v) {
#pragma unroll
  for (int m = 1; m < 64; m <<= 1) v += __shfl_xor(v, m, 64);
  return v;
}

__global__ void __launch_bounds__(THREADS) deepfit_kernel(
    const float* __restrict__ pts, const float* __restrict__ wts,
    float* __restrict__ beta_out, float* __restrict__ nest_out,
    float* __restrict__ nn_out)
{
  const int b = blockIdx.x;
  const int t = threadIdx.x;
  const int lane = t & 63;
  const int wid = t >> 6;

  __shared__ float s_red[4 * 38];
  __shared__ float s_mom[38];
  __shared__ float s_p1[4][3];
  __shared__ float s_hw[2];
  __shared__ float s_beta[10];
  __shared__ double s_L[100];
  __shared__ __attribute__((aligned(16))) float s_nn[NPTS * 3];

  const float4* px4 = reinterpret_cast<const float4*>(pts + (size_t)b * (3 * NPTS));
  const float4* pw4 = reinterpret_cast<const float4*>(wts + (size_t)b * NPTS);

  float4 x4 = px4[t];
  float4 y4 = px4[THREADS + t];
  float4 z4 = px4[2 * THREADS + t];
  float4 w4 = pw4[t];

  float xv[4] = {x4.x, x4.y, x4.z, x4.w};
  float yv[4] = {y4.x, y4.y, y4.z, y4.w};
  float zv[4] = {z4.x, z4.y, z4.z, z4.w};
  float wv[4] = {w4.x, w4.y, w4.z, w4.w};

  // ---- pass 1: h (mean |x| + mean |y|)/2 and valid count ----
  float sax = 0.f, say = 0.f, cntf = 0.f;
#pragma unroll
  for (int p = 0; p < 4; ++p) {
    sax += fabsf(xv[p]);
    say += fabsf(yv[p]);
    cntf += (wv[p] > 0.001f) ? 1.f : 0.f;
  }
  sax = wave_red_f(sax); say = wave_red_f(say); cntf = wave_red_f(cntf);
  if (lane == 0) { s_p1[wid][0] = sax; s_p1[wid][1] = say; s_p1[wid][2] = cntf; }
  __syncthreads();
  if (t == 0) {
    float ax = 0.f, ay = 0.f, c = 0.f;
#pragma unroll
    for (int i = 0; i < 4; ++i) { ax += s_p1[i][0]; ay += s_p1[i][1]; c += s_p1[i][2]; }
    float mh = (ax / (float)NPTS + ay / (float)NPTS) * 0.5f;
    if (fabsf(mh) < 1e-4f) mh = 0.1f;
    s_hw[0] = mh;
    s_hw[1] = (c > 18.f) ? 1.f : 0.f;
  }
  __syncthreads();
  const float h = s_hw[0];
  const float inv_h = 1.0f / h;
  const bool use_w = (s_hw[1] > 0.5f);

  // ---- pass 2: accumulate 28 moments w*x^a*y^b (a+b<=6) and 10 z-moments (a+b<=3) ----
  float M[28], Z[10];
#pragma unroll
  for (int i = 0; i < 28; ++i) M[i] = 0.f;
#pragma unroll
  for (int i = 0; i < 10; ++i) Z[i] = 0.f;

#pragma unroll
  for (int p = 0; p < 4; ++p) {
    float x = xv[p] * inv_h;
    float y = yv[p] * inv_h;
    xv[p] = x; yv[p] = y;           // keep scaled coords for the normals pass
    float w = use_w ? wv[p] : 1.0f;
    float wz = w * zv[p];
    float yp1 = y, yp2 = y * y, yp3 = yp2 * y, yp4 = yp3 * y, yp5 = yp4 * y, yp6 = yp5 * y;
    float tx = w;
    M[0] += tx; M[1] += tx * yp1; M[2] += tx * yp2; M[3] += tx * yp3; M[4] += tx * yp4; M[5] += tx * yp5; M[6] += tx * yp6;
    tx *= x;
    M[7] += tx; M[8] += tx * yp1; M[9] += tx * yp2; M[10] += tx * yp3; M[11] += tx * yp4; M[12] += tx * yp5;
    tx *= x;
    M[13] += tx; M[14] += tx * yp1; M[15] += tx * yp2; M[16] += tx * yp3; M[17] += tx * yp4;
    tx *= x;
    M[18] += tx; M[19] += tx * yp1; M[20] += tx * yp2; M[21] += tx * yp3;
    tx *= x;
    M[22] += tx; M[23] += tx * yp1; M[24] += tx * yp2;
    tx *= x;
    M[25] += tx; M[26] += tx * yp1;
    tx *= x;
    M[27] += tx;
    float tz = wz;
    Z[0] += tz; Z[1] += tz * yp1; Z[2] += tz * yp2; Z[3] += tz * yp3;
    tz *= x;
    Z[4] += tz; Z[5] += tz * yp1; Z[6] += tz * yp2;
    tz *= x;
    Z[7] += tz; Z[8] += tz * yp1;
    tz *= x;
    Z[9] += tz;
  }

#pragma unroll
  for (int i = 0; i < 28; ++i) {
    float v = wave_red_f(M[i]);
    if (lane == 0) s_red[wid * 38 + i] = v;
  }
#pragma unroll
  for (int i = 0; i < 10; ++i) {
    float v = wave_red_f(Z[i]);
    if (lane == 0) s_red[wid * 38 + 28 + i] = v;
  }
  __syncthreads();
  if (t < 38) {
    s_mom[t] = s_red[t] + s_red[38 + t] + s_red[76 + t] + s_red[114 + t];
  }
  __syncthreads();

  // ---- pass 3: lane-distributed (lanes 0..9 of wave 0) f64 Cholesky + solves ----
  if (wid == 0 && lane < 10) {
    const unsigned AXP = 0x18D21u;  // x-exponents of basis {x,y,x2,y2,xy,x3,y3,x2y,xy2,1}, 2b each
    const unsigned AYP = 0x27184u;  // y-exponents
    int axi = (AXP >> (2 * lane)) & 3;
    int ayi = (AYP >> (2 * lane)) & 3;
    constexpr int AXC[10] = {1,0,2,0,1,3,0,2,1,0};
    constexpr int AYC[10] = {0,1,0,2,1,0,3,1,2,0};
    double a[10];
    double yy;
#pragma unroll
    for (int j = 0; j < 10; ++j) {
      int as = axi + AXC[j];
      int bs2 = ayi + AYC[j];
      int idx = as * 7 - (as * (as - 1)) / 2 + bs2;   // moment index, a+b<=6
      a[j] = (double)s_mom[idx];
    }
    {
      int zi = axi * 4 - (axi * (axi - 1)) / 2 + ayi; // z-moment index, a+b<=3
      yy = (double)s_mom[28 + zi];
    }
    // right-looking Cholesky, column j broadcast via shfl; fused forward solve
    double Lc[10];
    double diag = 1.0;
#pragma unroll
    for (int j = 0; j < 10; ++j) {
      double ajj = __shfl(a[j], j, 64);
      double ljj = sqrt(ajj);
      double lij = (lane == j) ? ljj : a[j] / ljj;  // valid for lane >= j
      Lc[j] = lij;
      if (lane == j) diag = ljj;
      double uj = __shfl(yy, j, 64) / ljj;
      if (lane == j) yy = uj;
      else if (lane > j) yy -= lij * uj;
#pragma unroll
      for (int k = j + 1; k < 10; ++k) {
        double lkj = __shfl(lij, k, 64);
        a[k] -= lij * lkj;
      }
    }
#pragma unroll
    for (int j = 0; j < 10; ++j) s_L[lane * 10 + j] = Lc[j];
    asm volatile("s_waitcnt lgkmcnt(0)" ::: "memory");  // same-wave DS in-order; fence compiler
    // back solve L^T beta = u  (needs L[j][i] at lane i -> read transposed from LDS)
#pragma unroll
    for (int j = 9; j >= 0; --j) {
      double xj = __shfl(yy, j, 64) / __shfl(diag, j, 64);
      if (lane == j) yy = xj;
      else if (lane < j) yy -= s_L[j * 10 + lane] * xj;
    }
    int e = (0x3FEA5u >> (2 * lane)) & 3;  // d_inv exponent per beta component
    double ih = 1.0 / (double)h;
    double dsc = 1.0;
    if (e > 0) dsc = ih;
    if (e > 1) dsc *= ih;
    if (e > 2) dsc *= ih;
    double bsc = yy * dsc;
    s_beta[lane] = (float)bsc;
    beta_out[(size_t)b * 10 + lane] = (float)bsc;
    double b0 = __shfl(bsc, 0, 64);
    double b1 = __shfl(bsc, 1, 64);
    if (lane == 0) {
      double invn = 1.0 / sqrt(b0 * b0 + b1 * b1 + 1.0);
      nest_out[(size_t)b * 3 + 0] = (float)(-b0 * invn);
      nest_out[(size_t)b * 3 + 1] = (float)(-b1 * invn);
      nest_out[(size_t)b * 3 + 2] = (float)invn;
    }
  }
  __syncthreads();

  // ---- pass 4: neighbor normals (uses scaled x,y still in registers) ----
  float bb[10];
#pragma unroll
  for (int i = 0; i < 10; ++i) bb[i] = s_beta[i];
#pragma unroll
  for (int p = 0; p < 4; ++p) {
    float x = xv[p], y = yv[p];
    float x2 = x * x, y2 = y * y, xy = x * y;
    float nx = -(bb[0] + 2.f * bb[2] * x + bb[4] * y + 3.f * bb[5] * x2 + 2.f * bb[7] * xy + bb[8] * y2);
    float ny = -(bb[1] + 2.f * bb[3] * y + bb[4] * x + 3.f * bb[6] * y2 + bb[7] * x2 + 2.f * bb[8] * xy);
    float invn = 1.0f / sqrtf(nx * nx + ny * ny + 1.0f);
    int pidx = t * 4 + p;
    s_nn[pidx * 3 + 0] = nx * invn;
    s_nn[pidx * 3 + 1] = ny * invn;
    s_nn[pidx * 3 + 2] = invn;
  }
  __syncthreads();
  {
    const float4* s4 = reinterpret_cast<const float4*>(s_nn);
    float4* o4 = reinterpret_cast<float4*>(nn_out + (size_t)b * (NPTS * 3));
    o4[t] = s4[t];
    o4[THREADS + t] = s4[THREADS + t];
    o4[2 * THREADS + t] = s4[2 * THREADS + t];
  }
}

extern "C" void kernel_launch(void* const* d_in, const int* in_sizes, int n_in,
                              void* d_out, int out_size, void* d_ws, size_t ws_size,
                              hipStream_t stream) {
  const float* pts = (const float*)d_in[0];
  const float* wts = (const float*)d_in[1];
  float* out = (float*)d_out;
  const int B = in_sizes[1] / NPTS;
  float* beta_out = out;
  float* nest_out = out + (size_t)B * 10;
  float* nn_out = out + (size_t)B * 13;
  deepfit_kernel<<<B, THREADS, 0, stream>>>(pts, wts, beta_out, nest_out, nn_out);
}

// Round 2
// 62.861 us; speedup vs baseline: 1.9876x; 1.9876x over previous
//
#include <hip/hip_runtime.h>
#include <math.h>

#define NPTS 1024
#define THREADS 256

// --- DPP wave64 sum: result valid in lane 63; pure VALU, no DS-pipe ops ---
template <int CTRL>
__device__ __forceinline__ float dpp_add(float v) {
  int m = __builtin_amdgcn_update_dpp(0, __builtin_bit_cast(int, v), CTRL, 0xF, 0xF, true);
  return v + __builtin_bit_cast(float, m);
}

__device__ __forceinline__ float wave_red63(float v) {
  v = dpp_add<0x111>(v);  // row_shr:1
  v = dpp_add<0x112>(v);  // row_shr:2
  v = dpp_add<0x114>(v);  // row_shr:4
  v = dpp_add<0x118>(v);  // row_shr:8
  v = dpp_add<0x142>(v);  // row_bcast:15
  v = dpp_add<0x143>(v);  // row_bcast:31
  return v;               // lane 63 holds the full 64-lane sum
}

// --- uniform-index f64 broadcast via v_readlane (no ds_bpermute) ---
__device__ __forceinline__ double rl_f64(double v, int l) {
  typedef int v2i __attribute__((ext_vector_type(2)));
  v2i u = __builtin_bit_cast(v2i, v);
  v2i r;
  r.x = __builtin_amdgcn_readlane(u.x, l);
  r.y = __builtin_amdgcn_readlane(u.y, l);
  return __builtin_bit_cast(double, r);
}

__global__ void __launch_bounds__(THREADS) deepfit_kernel(
    const float* __restrict__ pts, const float* __restrict__ wts,
    float* __restrict__ beta_out, float* __restrict__ nest_out,
    float* __restrict__ nn_out)
{
  const int b = blockIdx.x;
  const int t = threadIdx.x;
  const int lane = t & 63;
  const int wid = t >> 6;

  __shared__ float s_red[4 * 38];
  __shared__ float s_mom[38];
  __shared__ float s_p1[4][3];
  __shared__ float s_hw[2];
  __shared__ float s_beta[10];
  __shared__ double s_L[100];

  const float4* px4 = reinterpret_cast<const float4*>(pts + (size_t)b * (3 * NPTS));
  const float4* pw4 = reinterpret_cast<const float4*>(wts + (size_t)b * NPTS);

  float4 x4 = px4[t];
  float4 y4 = px4[THREADS + t];
  float4 z4 = px4[2 * THREADS + t];
  float4 w4 = pw4[t];

  float xv[4] = {x4.x, x4.y, x4.z, x4.w};
  float yv[4] = {y4.x, y4.y, y4.z, y4.w};
  float zv[4] = {z4.x, z4.y, z4.z, z4.w};
  float wv[4] = {w4.x, w4.y, w4.z, w4.w};

  // ---- pass 1: h = (mean|x| + mean|y|)/2 and valid count ----
  float sax = 0.f, say = 0.f;
  int cnt = 0;
#pragma unroll
  for (int p = 0; p < 4; ++p) {
    sax += fabsf(xv[p]);
    say += fabsf(yv[p]);
    cnt += (int)__popcll(__ballot(wv[p] > 0.001f));  // wave-uniform count
  }
  sax = wave_red63(sax);
  say = wave_red63(say);
  if (lane == 63) { s_p1[wid][0] = sax; s_p1[wid][1] = say; }
  if (lane == 0) s_p1[wid][2] = (float)cnt;
  __syncthreads();
  if (t == 0) {
    float ax = 0.f, ay = 0.f, c = 0.f;
#pragma unroll
    for (int i = 0; i < 4; ++i) { ax += s_p1[i][0]; ay += s_p1[i][1]; c += s_p1[i][2]; }
    float mh = (ax / (float)NPTS + ay / (float)NPTS) * 0.5f;
    if (fabsf(mh) < 1e-4f) mh = 0.1f;
    s_hw[0] = mh;
    s_hw[1] = (c > 18.f) ? 1.f : 0.f;
  }
  __syncthreads();
  const float h = s_hw[0];
  const float inv_h = 1.0f / h;
  const bool use_w = (s_hw[1] > 0.5f);

  // ---- pass 2: 28 moments w*x^a*y^b (a+b<=6) + 10 z-moments (a+b<=3) ----
  float M[28], Z[10];
#pragma unroll
  for (int i = 0; i < 28; ++i) M[i] = 0.f;
#pragma unroll
  for (int i = 0; i < 10; ++i) Z[i] = 0.f;

#pragma unroll
  for (int p = 0; p < 4; ++p) {
    float x = xv[p] * inv_h;
    float y = yv[p] * inv_h;
    xv[p] = x; yv[p] = y;           // keep scaled coords for the normals pass
    float w = use_w ? wv[p] : 1.0f;
    float wz = w * zv[p];
    float yp1 = y, yp2 = y * y, yp3 = yp2 * y, yp4 = yp3 * y, yp5 = yp4 * y, yp6 = yp5 * y;
    float tx = w;
    M[0] += tx; M[1] += tx * yp1; M[2] += tx * yp2; M[3] += tx * yp3; M[4] += tx * yp4; M[5] += tx * yp5; M[6] += tx * yp6;
    tx *= x;
    M[7] += tx; M[8] += tx * yp1; M[9] += tx * yp2; M[10] += tx * yp3; M[11] += tx * yp4; M[12] += tx * yp5;
    tx *= x;
    M[13] += tx; M[14] += tx * yp1; M[15] += tx * yp2; M[16] += tx * yp3; M[17] += tx * yp4;
    tx *= x;
    M[18] += tx; M[19] += tx * yp1; M[20] += tx * yp2; M[21] += tx * yp3;
    tx *= x;
    M[22] += tx; M[23] += tx * yp1; M[24] += tx * yp2;
    tx *= x;
    M[25] += tx; M[26] += tx * yp1;
    tx *= x;
    M[27] += tx;
    float tz = wz;
    Z[0] += tz; Z[1] += tz * yp1; Z[2] += tz * yp2; Z[3] += tz * yp3;
    tz *= x;
    Z[4] += tz; Z[5] += tz * yp1; Z[6] += tz * yp2;
    tz *= x;
    Z[7] += tz; Z[8] += tz * yp1;
    tz *= x;
    Z[9] += tz;
  }

#pragma unroll
  for (int i = 0; i < 28; ++i) {
    float v = wave_red63(M[i]);
    if (lane == 63) s_red[wid * 38 + i] = v;
  }
#pragma unroll
  for (int i = 0; i < 10; ++i) {
    float v = wave_red63(Z[i]);
    if (lane == 63) s_red[wid * 38 + 28 + i] = v;
  }
  __syncthreads();
  if (t < 38) {
    s_mom[t] = s_red[t] + s_red[38 + t] + s_red[76 + t] + s_red[114 + t];
  }
  __syncthreads();

  // ---- pass 3: lane-distributed (lanes 0..9 of wave 0) f64 Cholesky + solves ----
  if (wid == 0 && lane < 10) {
    const unsigned AXP = 0x18D21u;  // x-exponents of basis {x,y,x2,y2,xy,x3,y3,x2y,xy2,1}
    const unsigned AYP = 0x27184u;  // y-exponents
    int axi = (AXP >> (2 * lane)) & 3;
    int ayi = (AYP >> (2 * lane)) & 3;
    constexpr int AXC[10] = {1,0,2,0,1,3,0,2,1,0};
    constexpr int AYC[10] = {0,1,0,2,1,0,3,1,2,0};
    double a[10];
    double yy;
#pragma unroll
    for (int j = 0; j < 10; ++j) {
      int as = axi + AXC[j];
      int bs2 = ayi + AYC[j];
      int idx = as * 7 - (as * (as - 1)) / 2 + bs2;   // moment index, a+b<=6
      a[j] = (double)s_mom[idx];
    }
    {
      int zi = axi * 4 - (axi * (axi - 1)) / 2 + ayi; // z-moment index, a+b<=3
      yy = (double)s_mom[28 + zi];
    }
    // right-looking Cholesky; broadcasts via v_readlane (uniform indices), no DS ops
    double Lc[10];
    double rdiag = 1.0;
#pragma unroll
    for (int j = 0; j < 10; ++j) {
      double ajj = rl_f64(a[j], j);
      double ljj = sqrt(ajj);
      double rljj = 1.0 / ljj;
      double lij = (lane == j) ? ljj : a[j] * rljj;  // valid for lane >= j
      Lc[j] = lij;
      if (lane == j) rdiag = rljj;
      double uj = rl_f64(yy, j) * rljj;
      if (lane == j) yy = uj;
      else if (lane > j) yy -= lij * uj;
#pragma unroll
      for (int k = j + 1; k < 10; ++k) {
        double lkj = rl_f64(lij, k);
        a[k] -= lij * lkj;
      }
    }
#pragma unroll
    for (int j = 0; j < 10; ++j) s_L[lane * 10 + j] = Lc[j];
    asm volatile("s_waitcnt lgkmcnt(0)" ::: "memory");  // same-wave DS in-order; fence compiler
    // back solve L^T beta = u (lane i needs L[j][i] -> transposed read from LDS)
#pragma unroll
    for (int j = 9; j >= 0; --j) {
      double xj = rl_f64(yy, j) * rl_f64(rdiag, j);
      if (lane == j) yy = xj;
      else if (lane < j) yy -= s_L[j * 10 + lane] * xj;
    }
    int e = (0x3FEA5u >> (2 * lane)) & 3;  // d_inv exponent per beta component
    double ih = 1.0 / (double)h;
    double dsc = 1.0;
    if (e > 0) dsc = ih;
    if (e > 1) dsc *= ih;
    if (e > 2) dsc *= ih;
    double bsc = yy * dsc;
    s_beta[lane] = (float)bsc;
    beta_out[(size_t)b * 10 + lane] = (float)bsc;
    double b0 = rl_f64(bsc, 0);
    double b1 = rl_f64(bsc, 1);
    if (lane == 0) {
      double invn = 1.0 / sqrt(b0 * b0 + b1 * b1 + 1.0);
      nest_out[(size_t)b * 3 + 0] = (float)(-b0 * invn);
      nest_out[(size_t)b * 3 + 1] = (float)(-b1 * invn);
      nest_out[(size_t)b * 3 + 2] = (float)invn;
    }
  }
  __syncthreads();

  // ---- pass 4: neighbor normals; thread t owns points 4t..4t+3 -> 12 contiguous
  //      output floats = exactly 3 float4 stores, no LDS staging ----
  float bb[10];
#pragma unroll
  for (int i = 0; i < 10; ++i) bb[i] = s_beta[i];
  float nx[4], ny[4], nz[4];
#pragma unroll
  for (int p = 0; p < 4; ++p) {
    float x = xv[p], y = yv[p];
    float x2 = x * x, y2 = y * y, xy = x * y;
    float vx = -(bb[0] + 2.f * bb[2] * x + bb[4] * y + 3.f * bb[5] * x2 + 2.f * bb[7] * xy + bb[8] * y2);
    float vy = -(bb[1] + 2.f * bb[3] * y + bb[4] * x + 3.f * bb[6] * y2 + bb[7] * x2 + 2.f * bb[8] * xy);
    float invn = 1.0f / sqrtf(vx * vx + vy * vy + 1.0f);
    nx[p] = vx * invn; ny[p] = vy * invn; nz[p] = invn;
  }
  {
    float4* o4 = reinterpret_cast<float4*>(nn_out + (size_t)b * (NPTS * 3));
    float4 f0 = make_float4(nx[0], ny[0], nz[0], nx[1]);
    float4 f1 = make_float4(ny[1], nz[1], nx[2], ny[2]);
    float4 f2 = make_float4(nz[2], nx[3], ny[3], nz[3]);
    o4[3 * t + 0] = f0;
    o4[3 * t + 1] = f1;
    o4[3 * t + 2] = f2;
  }
}

extern "C" void kernel_launch(void* const* d_in, const int* in_sizes, int n_in,
                              void* d_out, int out_size, void* d_ws, size_t ws_size,
                              hipStream_t stream) {
  const float* pts = (const float*)d_in[0];
  const float* wts = (const float*)d_in[1];
  float* out = (float*)d_out;
  const int B = in_sizes[1] / NPTS;
  float* beta_out = out;
  float* nest_out = out + (size_t)B * 10;
  float* nn_out = out + (size_t)B * 13;
  deepfit_kernel<<<B, THREADS, 0, stream>>>(pts, wts, beta_out, nest_out, nn_out);
}

// Round 3
// 56.079 us; speedup vs baseline: 2.2280x; 1.1209x over previous
//
#include <hip/hip_runtime.h>
#include <math.h>

#define NPTS 1024
#define THREADS 256

template <int CTRL>
__device__ __forceinline__ float dpp_add(float v) {
  int m = __builtin_amdgcn_update_dpp(0, __builtin_bit_cast(int, v), CTRL, 0xF, 0xF, true);
  return v + __builtin_bit_cast(float, m);
}

// 4-step reduction within rows of 16: lanes 15,31,47,63 hold their row sums
__device__ __forceinline__ float row_red16(float v) {
  v = dpp_add<0x111>(v);  // row_shr:1
  v = dpp_add<0x112>(v);  // row_shr:2
  v = dpp_add<0x114>(v);  // row_shr:4
  v = dpp_add<0x118>(v);  // row_shr:8
  return v;
}

__device__ __forceinline__ double rl_f64(double v, int l) {
  typedef int v2i __attribute__((ext_vector_type(2)));
  v2i u = __builtin_bit_cast(v2i, v);
  v2i r;
  r.x = __builtin_amdgcn_readlane(u.x, l);
  r.y = __builtin_amdgcn_readlane(u.y, l);
  return __builtin_bit_cast(double, r);
}

__device__ __forceinline__ float bperm_f(int srclane, float v) {
  return __builtin_bit_cast(float,
      __builtin_amdgcn_ds_bpermute(srclane << 2, __builtin_bit_cast(int, v)));
}

__global__ void __launch_bounds__(THREADS) deepfit_kernel(
    const float* __restrict__ pts, const float* __restrict__ wts,
    float* __restrict__ beta_out, float* __restrict__ nest_out,
    float* __restrict__ nn_out)
{
  const int b = blockIdx.x;
  const int t = threadIdx.x;
  const int lane = t & 63;
  const int wid = t >> 6;

  __shared__ __attribute__((aligned(16))) float s_red[39][16];
  __shared__ int s_cnt[4];
  __shared__ int s_redo;
  __shared__ float s_hw;
  __shared__ float s_beta[10];
  __shared__ double s_L[100];

  const float4* px4 = reinterpret_cast<const float4*>(pts + (size_t)b * (3 * NPTS));
  const float4* pw4 = reinterpret_cast<const float4*>(wts + (size_t)b * NPTS);

  float4 x4 = px4[t];
  float4 y4 = px4[THREADS + t];
  float4 z4 = px4[2 * THREADS + t];
  float4 w4 = pw4[t];

  float xv[4] = {x4.x, x4.y, x4.z, x4.w};
  float yv[4] = {y4.x, y4.y, y4.z, y4.w};
  float zv[4] = {z4.x, z4.y, z4.z, z4.w};
  float wv[4] = {w4.x, w4.y, w4.z, w4.w};

  // ---- h partial (|x|+|y| summed together; h = total/(2N)) and valid count ----
  float habs = 0.f;
  int cnt = 0;
#pragma unroll
  for (int p = 0; p < 4; ++p) {
    habs += fabsf(xv[p]) + fabsf(yv[p]);
    cnt += (int)__popcll(__ballot(wv[p] > 0.001f));
  }
  habs = row_red16(habs);
  if ((lane & 15) == 15) s_red[38][wid * 4 + (lane >> 4)] = habs;
  if (lane == 0) s_cnt[wid] = cnt;

  // ---- main loop: moments with w (optimistic); redo with w=1 only if count<=18 ----
  bool wone = false;
  for (int it = 0; it < 2; ++it) {
    // RAW moments (no h scaling -- h cancels exactly in beta): 28 of w*x^a*y^b
    // (a+b<=6) and 10 of w*z*x^a*y^b (a+b<=3)
    float M[28], Z[10];
#pragma unroll
    for (int i = 0; i < 28; ++i) M[i] = 0.f;
#pragma unroll
    for (int i = 0; i < 10; ++i) Z[i] = 0.f;

#pragma unroll
    for (int p = 0; p < 4; ++p) {
      float x = xv[p];
      float y = yv[p];
      float w = wone ? 1.0f : wv[p];
      float wz = w * zv[p];
      float yp1 = y, yp2 = y * y, yp3 = yp2 * y, yp4 = yp3 * y, yp5 = yp4 * y, yp6 = yp5 * y;
      float tx = w;
      M[0] += tx; M[1] += tx * yp1; M[2] += tx * yp2; M[3] += tx * yp3; M[4] += tx * yp4; M[5] += tx * yp5; M[6] += tx * yp6;
      tx *= x;
      M[7] += tx; M[8] += tx * yp1; M[9] += tx * yp2; M[10] += tx * yp3; M[11] += tx * yp4; M[12] += tx * yp5;
      tx *= x;
      M[13] += tx; M[14] += tx * yp1; M[15] += tx * yp2; M[16] += tx * yp3; M[17] += tx * yp4;
      tx *= x;
      M[18] += tx; M[19] += tx * yp1; M[20] += tx * yp2; M[21] += tx * yp3;
      tx *= x;
      M[22] += tx; M[23] += tx * yp1; M[24] += tx * yp2;
      tx *= x;
      M[25] += tx; M[26] += tx * yp1;
      tx *= x;
      M[27] += tx;
      float tz = wz;
      Z[0] += tz; Z[1] += tz * yp1; Z[2] += tz * yp2; Z[3] += tz * yp3;
      tz *= x;
      Z[4] += tz; Z[5] += tz * yp1; Z[6] += tz * yp2;
      tz *= x;
      Z[7] += tz; Z[8] += tz * yp1;
      tz *= x;
      Z[9] += tz;
    }

#pragma unroll
    for (int i = 0; i < 28; ++i) {
      float v = row_red16(M[i]);
      if ((lane & 15) == 15) s_red[i][wid * 4 + (lane >> 4)] = v;
    }
#pragma unroll
    for (int i = 0; i < 10; ++i) {
      float v = row_red16(Z[i]);
      if ((lane & 15) == 15) s_red[28 + i][wid * 4 + (lane >> 4)] = v;
    }
    __syncthreads();  // B1: partials published

    if (wid == 0) {
      // combine: lane r (<39) sums the 16 partials of value r
      float rowsum = 0.f;
      if (lane < 39) {
        const float4* r4 = reinterpret_cast<const float4*>(&s_red[lane][0]);
        float4 a0 = r4[0], a1 = r4[1], a2 = r4[2], a3 = r4[3];
        rowsum = ((a0.x + a0.y) + (a0.z + a0.w)) + ((a1.x + a1.y) + (a1.z + a1.w)) +
                 ((a2.x + a2.y) + (a2.z + a2.w)) + ((a3.x + a3.y) + (a3.z + a3.w));
      }
      int ctot = s_cnt[0] + s_cnt[1] + s_cnt[2] + s_cnt[3];
      float hs = __builtin_bit_cast(float,
          __builtin_amdgcn_readlane(__builtin_bit_cast(int, rowsum), 38));
      float mh = hs * (1.0f / 2048.0f);  // (mean|x|+mean|y|)/2
      if (fabsf(mh) < 1e-4f) mh = 0.1f;
      bool redo = (it == 0) && (ctot <= 18);
      if (lane == 0) { s_redo = redo ? 1 : 0; s_hw = mh; }

      if (!redo) {
        // gather row `lane` of raw XtX (10 moments) + rhs via ds_bpermute
        const int lc = (lane < 10) ? lane : 0;
        const int axi = (0x18D21u >> (2 * lc)) & 3;  // x-exp of basis {x,y,x2,y2,xy,x3,y3,x2y,xy2,1}
        const int ayi = (0x27184u >> (2 * lc)) & 3;  // y-exp
        constexpr int AXC[10] = {1, 0, 2, 0, 1, 3, 0, 2, 1, 0};
        constexpr int AYC[10] = {0, 1, 0, 2, 1, 0, 3, 1, 2, 0};
        double a[10], yy;
#pragma unroll
        for (int j = 0; j < 10; ++j) {
          int as = axi + AXC[j];
          int bs = ayi + AYC[j];
          int idx = as * 7 - (as * (as - 1)) / 2 + bs;  // moment index, a+b<=6
          a[j] = (double)bperm_f(idx, rowsum);
        }
        {
          int zi = axi * 4 - (axi * (axi - 1)) / 2 + ayi;  // z-moment index, a+b<=3
          yy = (double)bperm_f(28 + zi, rowsum);
        }

        if (lane < 10) {
          // LDL^T (no sqrt; one f64 divide per column), lane i = row i
          double Lc[10];
          double rd_own = 1.0;
#pragma unroll
          for (int j = 0; j < 10; ++j) {
            double dj = rl_f64(a[j], j);
            double rdj = 1.0 / dj;
            double lij = a[j] * rdj;  // L[i][j] for i>j (lane j: ~1)
            Lc[j] = lij;
            if (lane == j) rd_own = rdj;
            double wj = rl_f64(yy, j);
            if (lane > j) yy -= lij * wj;  // forward solve L w = y
#pragma unroll
            for (int k = j + 1; k < 10; ++k) {
              double ajk = rl_f64(a[k], j);  // A[j][k] (pre-update at lane j)
              a[k] -= lij * ajk;             // trailing update
            }
          }
          yy *= rd_own;  // D^{-1}
          // store L for transposed access in the back solve
#pragma unroll
          for (int j = 0; j < 10; ++j) s_L[lane * 10 + j] = Lc[j];
          asm volatile("s_waitcnt lgkmcnt(0)" ::: "memory");  // same-wave DS in-order
#pragma unroll
          for (int j = 9; j >= 0; --j) {  // back solve L^T beta = v (unit diag)
            double xj = rl_f64(yy, j);
            if (lane < j) yy -= s_L[j * 10 + lane] * xj;
          }
          // h cancels: raw solve IS the final beta
          float bf = (float)yy;
          s_beta[lane] = bf;
          beta_out[(size_t)b * 10 + lane] = bf;
          double b0 = rl_f64(yy, 0);
          double b1 = rl_f64(yy, 1);
          if (lane == 0) {
            double invn = 1.0 / sqrt(b0 * b0 + b1 * b1 + 1.0);
            nest_out[(size_t)b * 3 + 0] = (float)(-b0 * invn);
            nest_out[(size_t)b * 3 + 1] = (float)(-b1 * invn);
            nest_out[(size_t)b * 3 + 2] = (float)invn;
          }
        }
      }
    }
    __syncthreads();  // B2: beta/h/redo published
    if (s_redo == 0) break;
    wone = true;
  }

  // ---- normals: scaled coords x/h, y/h with final beta ----
  const float h = s_hw;
  const float inv_h = 1.0f / h;
  float bb[10];
#pragma unroll
  for (int i = 0; i < 10; ++i) bb[i] = s_beta[i];
  float nx[4], ny[4], nz[4];
#pragma unroll
  for (int p = 0; p < 4; ++p) {
    float x = xv[p] * inv_h;
    float y = yv[p] * inv_h;
    float x2 = x * x, y2 = y * y, xy = x * y;
    float vx = -(bb[0] + 2.f * bb[2] * x + bb[4] * y + 3.f * bb[5] * x2 + 2.f * bb[7] * xy + bb[8] * y2);
    float vy = -(bb[1] + 2.f * bb[3] * y + bb[4] * x + 3.f * bb[6] * y2 + bb[7] * x2 + 2.f * bb[8] * xy);
    float invn = 1.0f / sqrtf(vx * vx + vy * vy + 1.0f);
    nx[p] = vx * invn; ny[p] = vy * invn; nz[p] = invn;
  }
  {
    float4* o4 = reinterpret_cast<float4*>(nn_out + (size_t)b * (NPTS * 3));
    float4 f0 = make_float4(nx[0], ny[0], nz[0], nx[1]);
    float4 f1 = make_float4(ny[1], nz[1], nx[2], ny[2]);
    float4 f2 = make_float4(nz[2], nx[3], ny[3], nz[3]);
    o4[3 * t + 0] = f0;
    o4[3 * t + 1] = f1;
    o4[3 * t + 2] = f2;
  }
}

extern "C" void kernel_launch(void* const* d_in, const int* in_sizes, int n_in,
                              void* d_out, int out_size, void* d_ws, size_t ws_size,
                              hipStream_t stream) {
  const float* pts = (const float*)d_in[0];
  const float* wts = (const float*)d_in[1];
  float* out = (float*)d_out;
  const int B = in_sizes[1] / NPTS;
  float* beta_out = out;
  float* nest_out = out + (size_t)B * 10;
  float* nn_out = out + (size_t)B * 13;
  deepfit_kernel<<<B, THREADS, 0, stream>>>(pts, wts, beta_out, nest_out, nn_out);
}